// Round 2
// baseline (5324.006 us; speedup 1.0000x reference)
//
#include <hip/hip_runtime.h>
#include <hip/hip_bf16.h>

#define CDIV(a,b) (((a)+(b)-1)/(b))

typedef __attribute__((ext_vector_type(8))) short s8v;   // 8 x bf16 bits
typedef __attribute__((ext_vector_type(4))) float f4v;   // MFMA acc

static __device__ __forceinline__ unsigned short f2bf(float f) {
  unsigned int u = __float_as_uint(f);
  u += 0x7fffu + ((u >> 16) & 1u);           // round-nearest-even
  return (unsigned short)(u >> 16);
}

// ---------------- weight preprocessing ----------------
// w1 [3][128][512] f32 -> w1t [3][512][128] bf16 (n-major, k contiguous)
__global__ void k_w1t(const float* __restrict__ w1, unsigned short* __restrict__ w1t) {
  int idx = blockIdx.x * 256 + threadIdx.x;
  if (idx >= 3 * 512 * 128) return;
  int p = idx >> 16;           // /65536
  int rem = idx & 65535;
  int n = rem >> 7, k = rem & 127;
  w1t[idx] = f2bf(w1[p * 65536 + k * 512 + n]);
}

// w2 [2][1536][40] f32 -> w2t [80][1536] bf16; col j<40 from w2[0], j>=40 from w2[1]
__global__ void k_w2t(const float* __restrict__ w2, unsigned short* __restrict__ w2t) {
  int idx = blockIdx.x * 256 + threadIdx.x;
  if (idx >= 80 * 1536) return;
  int j = idx / 1536, k = idx % 1536;
  int g  = (j < 40) ? 0 : 1;
  int jj = (j < 40) ? j : j - 40;
  w2t[idx] = f2bf(w2[g * 61440 + k * 40 + jj]);
}

// ---------------- gcn_norm ----------------
__global__ void k_fill1(float* __restrict__ deg, int n) {
  int i = blockIdx.x * 256 + threadIdx.x;
  if (i < n) deg[i] = 1.0f;                  // self loop
}
__global__ void k_deg(const int* __restrict__ col, float* __restrict__ deg, int E) {
  int i = blockIdx.x * 256 + threadIdx.x;
  if (i < E) atomicAdd(&deg[col[i]], 1.0f);
}
__global__ void k_rsqrt(float* __restrict__ deg, int n) {
  int i = blockIdx.x * 256 + threadIdx.x;
  if (i < n) deg[i] = rsqrtf(deg[i]);        // deg>=1 always
}
__global__ void k_norm(const int* __restrict__ row, const int* __restrict__ col,
                       const float* __restrict__ dinv, float* __restrict__ nrm, int E) {
  int i = blockIdx.x * 256 + threadIdx.x;
  if (i < E) nrm[i] = dinv[row[i]] * dinv[col[i]];
}

// ---------------- SpMM (atomic scatter) ----------------
// dst[n,:] = dinv[n]^2 * src[n,:]   (self-loop term / init), float4 per thread
__global__ void k_selfinit(const float* __restrict__ src, const float* __restrict__ dinv,
                           float* __restrict__ dst, int nvec4, int fdiv4) {
  int i = blockIdx.x * 256 + threadIdx.x;
  if (i >= nvec4) return;
  int n = i / fdiv4;
  float d = dinv[n]; d *= d;
  float4 v = ((const float4*)src)[i];
  v.x *= d; v.y *= d; v.z *= d; v.w *= d;
  ((float4*)dst)[i] = v;
}

// width 128: one wave per edge, float2 per lane
__global__ void k_edges128(const int* __restrict__ row, const int* __restrict__ col,
                           const float* __restrict__ nrm, const float* __restrict__ src,
                           float* __restrict__ dst, int E) {
  int e = blockIdx.x * 4 + (threadIdx.x >> 6);
  if (e >= E) return;
  int lane = threadIdx.x & 63;
  int r = row[e], c = col[e];
  float w = nrm[e];
  const float2 v = *(const float2*)(src + (size_t)r * 128 + lane * 2);
  float* d = dst + (size_t)c * 128 + lane * 2;
  atomicAdd(d,     w * v.x);
  atomicAdd(d + 1, w * v.y);
}

// width 40: one wave per edge, lanes 0..39 active
__global__ void k_edges40(const int* __restrict__ row, const int* __restrict__ col,
                          const float* __restrict__ nrm, const float* __restrict__ src,
                          float* __restrict__ dst, int E) {
  int e = blockIdx.x * 4 + (threadIdx.x >> 6);
  if (e >= E) return;
  int lane = threadIdx.x & 63;
  if (lane >= 40) return;
  int r = row[e], c = col[e];
  atomicAdd(dst + (size_t)c * 40 + lane, nrm[e] * src[(size_t)r * 40 + lane]);
}

// ---------------- GEMM 1: C = relu(A[M,128] @ B[128,512] + b1), bf16 out into H cols ----------------
// block: 256 thr (4 waves), 64 rows; wave w owns cols [w*128, w*128+128)
// A is pre-offset to the chunk base; M is the chunk row count; H is chunk-local.
__global__ __launch_bounds__(256) void k_gemm1(
    const float* __restrict__ A, const unsigned short* __restrict__ Bt,
    const float* __restrict__ bias, unsigned short* __restrict__ H,
    int M, int col0) {
  __shared__ unsigned short Als[64 * 136];   // +8 pad keeps 16B align, spreads banks
  const int tid = threadIdx.x;
  const int row0 = blockIdx.x * 64;
#pragma unroll
  for (int it = 0; it < 8; ++it) {
    int f = it * 256 + tid;                  // float4 index over 64x128
    int r = f >> 5;
    int c = (f & 31) << 2;
    int gr = row0 + r; if (gr > M - 1) gr = M - 1;
    const float4 v = *(const float4*)(A + (size_t)gr * 128 + c);
    unsigned short* d = &Als[r * 136 + c];
    d[0] = f2bf(v.x); d[1] = f2bf(v.y); d[2] = f2bf(v.z); d[3] = f2bf(v.w);
  }
  __syncthreads();
  const int wave = tid >> 6, lane = tid & 63;
  const int lhi = lane >> 4, llo = lane & 15;
  f4v acc[4][8];
#pragma unroll
  for (int i = 0; i < 4; ++i)
#pragma unroll
    for (int j = 0; j < 8; ++j) acc[i][j] = (f4v){0.f, 0.f, 0.f, 0.f};
  const unsigned short* Bw = Bt + (size_t)(wave * 128 + llo) * 128 + lhi * 8;
#pragma unroll
  for (int kk = 0; kk < 128; kk += 32) {
    s8v a[4], b[8];
#pragma unroll
    for (int i = 0; i < 4; ++i)
      a[i] = *(const s8v*)&Als[(i * 16 + llo) * 136 + kk + lhi * 8];
#pragma unroll
    for (int j = 0; j < 8; ++j)
      b[j] = *(const s8v*)(Bw + (size_t)j * 16 * 128 + kk);
#pragma unroll
    for (int i = 0; i < 4; ++i)
#pragma unroll
      for (int j = 0; j < 8; ++j)
        acc[i][j] = __builtin_amdgcn_mfma_f32_16x16x32_bf16(a[i], b[j], acc[i][j], 0, 0, 0);
  }
#pragma unroll
  for (int i = 0; i < 4; ++i) {
#pragma unroll
    for (int j = 0; j < 8; ++j) {
      int colg = col0 + wave * 128 + j * 16 + llo;
      float bv = bias[colg];
#pragma unroll
      for (int r = 0; r < 4; ++r) {
        int rowg = row0 + i * 16 + lhi * 4 + r;
        if (rowg < M) {
          float v = acc[i][j][r] + bv;
          H[(size_t)rowg * 1536 + colg] = f2bf(v > 0.f ? v : 0.f);
        }
      }
    }
  }
}

// ---------------- GEMM 2: [M,1536]bf16 @ [1536,80] -> t0(+b2) into out[:,0:40], t1 to ws ----------------
// block: 256 thr (4 waves); wave w owns rows [blk*256 + w*64, +64), all 80 cols
// Hm chunk-local; out/t1 pre-offset to chunk base.
__global__ __launch_bounds__(256) void k_gemm2(
    const unsigned short* __restrict__ Hm, const unsigned short* __restrict__ Bt,
    const float* __restrict__ b2, float* __restrict__ out, float* __restrict__ t1, int M) {
  const int tid = threadIdx.x, wave = tid >> 6, lane = tid & 63;
  const int lhi = lane >> 4, llo = lane & 15;
  const int row0 = blockIdx.x * 256 + wave * 64;
  f4v acc[4][5];
#pragma unroll
  for (int i = 0; i < 4; ++i)
#pragma unroll
    for (int j = 0; j < 5; ++j) acc[i][j] = (f4v){0.f, 0.f, 0.f, 0.f};
  size_t arow[4];
#pragma unroll
  for (int i = 0; i < 4; ++i) {
    int r = row0 + i * 16 + llo; if (r > M - 1) r = M - 1;
    arow[i] = (size_t)r * 1536 + lhi * 8;
  }
  const unsigned short* Bw = Bt + (size_t)llo * 1536 + lhi * 8;
  for (int kk = 0; kk < 1536; kk += 32) {
    s8v a[4], b[5];
#pragma unroll
    for (int i = 0; i < 4; ++i) a[i] = *(const s8v*)(Hm + arow[i] + kk);
#pragma unroll
    for (int j = 0; j < 5; ++j) b[j] = *(const s8v*)(Bw + (size_t)j * 16 * 1536 + kk);
#pragma unroll
    for (int i = 0; i < 4; ++i)
#pragma unroll
      for (int j = 0; j < 5; ++j)
        acc[i][j] = __builtin_amdgcn_mfma_f32_16x16x32_bf16(a[i], b[j], acc[i][j], 0, 0, 0);
  }
#pragma unroll
  for (int i = 0; i < 4; ++i)
#pragma unroll
    for (int j = 0; j < 5; ++j) {
      int col = j * 16 + llo;
#pragma unroll
      for (int r = 0; r < 4; ++r) {
        int rowg = row0 + i * 16 + lhi * 4 + r;
        if (rowg < M) {
          float v = acc[i][j][r];
          if (col < 40) out[(size_t)rowg * 80 + col] = v + b2[col];
          else          t1[(size_t)rowg * 40 + col - 40] = v;
        }
      }
    }
}

// ---------------- log_softmax over 80 cols; one wave per row ----------------
__global__ void k_logsm(float* __restrict__ out, const float* __restrict__ u1,
                        const float* __restrict__ b2, int N) {
  int n = blockIdx.x * 4 + (threadIdx.x >> 6);
  if (n >= N) return;
  int lane = threadIdx.x & 63;
  float v0, v1;
  if (lane < 40) v0 = out[(size_t)n * 80 + lane];
  else           v0 = u1[(size_t)n * 40 + lane - 40] + b2[lane];
  v1 = (lane < 16) ? (u1[(size_t)n * 40 + 24 + lane] + b2[64 + lane]) : -INFINITY;
  float m = fmaxf(v0, v1);
#pragma unroll
  for (int s = 32; s > 0; s >>= 1) m = fmaxf(m, __shfl_xor(m, s));
  float s = __expf(v0 - m) + ((lane < 16) ? __expf(v1 - m) : 0.f);
#pragma unroll
  for (int sft = 32; sft > 0; sft >>= 1) s += __shfl_xor(s, sft);
  float L = m + __logf(s);
  out[(size_t)n * 80 + lane] = v0 - L;
  if (lane < 16) out[(size_t)n * 80 + 64 + lane] = v1 - L;
}

// ---------------- launch ----------------
extern "C" void kernel_launch(void* const* d_in, const int* in_sizes, int n_in,
                              void* d_out, int out_size, void* d_ws, size_t ws_size,
                              hipStream_t stream) {
  const float* x  = (const float*)d_in[0];
  const int*   ei = (const int*)d_in[1];
  const float* w1 = (const float*)d_in[2];
  const float* b1 = (const float*)d_in[3];
  const float* w2 = (const float*)d_in[4];
  const float* b2 = (const float*)d_in[5];
  float* out = (float*)d_out;

  const int N = in_sizes[0] / 128;
  const int E = in_sizes[1] / 2;
  const int* erow = ei;
  const int* ecol = ei + E;

  // workspace carve (256B aligned). Fixed part ~211 MB; Hb sized from ws_size.
  char* p = (char*)d_ws;
  auto carve = [&](size_t bytes) { void* r = (void*)p; p += (bytes + 255) & ~(size_t)255; return r; };
  float*          deg  = (float*)carve((size_t)N * 4);            // becomes dinv in place
  float*          nrm  = (float*)carve((size_t)E * 4);
  float*          h1   = (float*)carve((size_t)N * 128 * 4);
  float*          h2   = (float*)carve((size_t)N * 128 * 4);
  float*          t1   = (float*)carve((size_t)N * 40 * 4);       // own region (chunking)
  unsigned short* w1t  = (unsigned short*)carve((size_t)3 * 512 * 128 * 2);
  unsigned short* w2t  = (unsigned short*)carve((size_t)80 * 1536 * 2);
  float*          u1   = h2;   // h2 dead after the chunk loop completes

  // Hb chunk rows from remaining workspace
  size_t usedB = (size_t)(p - (char*)d_ws);
  size_t remB  = (ws_size > usedB + (1u << 20)) ? (ws_size - usedB - (1u << 20)) : 0;
  long long cap = (long long)(remB / (1536 * 2));
  int Cmax = (cap >= (long long)N) ? N : (int)cap;
  Cmax &= ~63;
  if (Cmax < 64) Cmax = 64;    // if ws is truly tiny nothing valid exists; assume not
  unsigned short* Hb = (unsigned short*)carve((size_t)Cmax * 1536 * 2);

  // weights -> bf16 transposed
  k_w1t<<<CDIV(3 * 512 * 128, 256), 256, 0, stream>>>(w1, w1t);
  k_w2t<<<CDIV(80 * 1536, 256), 256, 0, stream>>>(w2, w2t);

  // gcn_norm
  k_fill1<<<CDIV(N, 256), 256, 0, stream>>>(deg, N);
  k_deg  <<<CDIV(E, 256), 256, 0, stream>>>(ecol, deg, E);
  k_rsqrt<<<CDIV(N, 256), 256, 0, stream>>>(deg, N);
  k_norm <<<CDIV(E, 256), 256, 0, stream>>>(erow, ecol, deg, nrm, E);

  // h1 = A_hat x ; h2 = A_hat h1   (width 128)
  k_selfinit<<<CDIV(N * 32, 256), 256, 0, stream>>>(x,  deg, h1, N * 32, 32);
  k_edges128<<<CDIV(E, 4), 256, 0, stream>>>(erow, ecol, nrm, x,  h1, E);
  k_selfinit<<<CDIV(N * 32, 256), 256, 0, stream>>>(h1, deg, h2, N * 32, 32);
  k_edges128<<<CDIV(E, 4), 256, 0, stream>>>(erow, ecol, nrm, h1, h2, E);

  // chunked: H = relu(concat(xW0, h1W1, h2W2) + b1); t0 -> out[:,0:40]+b2; t1 = H @ w2[1]
  for (int r0 = 0; r0 < N; r0 += Cmax) {
    int Mc = (N - r0 < Cmax) ? (N - r0) : Cmax;
    int g1 = CDIV(Mc, 64);
    k_gemm1<<<g1, 256, 0, stream>>>(x  + (size_t)r0 * 128, w1t,          b1, Hb, Mc, 0);
    k_gemm1<<<g1, 256, 0, stream>>>(h1 + (size_t)r0 * 128, w1t +  65536, b1, Hb, Mc, 512);
    k_gemm1<<<g1, 256, 0, stream>>>(h2 + (size_t)r0 * 128, w1t + 131072, b1, Hb, Mc, 1024);
    k_gemm2<<<CDIV(Mc, 256), 256, 0, stream>>>(Hb, w2t, b2,
                                               out + (size_t)r0 * 80,
                                               t1  + (size_t)r0 * 40, Mc);
  }

  // u1 = A_hat t1  (width 40); u1 aliases h2 (dead now)
  k_selfinit<<<CDIV(N * 10, 256), 256, 0, stream>>>(t1, deg, u1, N * 10, 10);
  k_edges40<<<CDIV(E, 4), 256, 0, stream>>>(erow, ecol, nrm, t1, u1, E);

  // out = log_softmax([t0+b2[0:40], u1+b2[40:80]])
  k_logsm<<<CDIV(N, 4), 256, 0, stream>>>(out, u1, b2, N);
}

// Round 3
// 1729.846 us; speedup vs baseline: 3.0777x; 3.0777x over previous
//
#include <hip/hip_runtime.h>
#include <hip/hip_bf16.h>

#define CDIV(a,b) (((a)+(b)-1)/(b))

typedef __attribute__((ext_vector_type(8))) short s8v;   // 8 x bf16 bits
typedef __attribute__((ext_vector_type(4))) float f4v;   // MFMA acc

static __device__ __forceinline__ unsigned short f2bf(float f) {
  unsigned int u = __float_as_uint(f);
  u += 0x7fffu + ((u >> 16) & 1u);           // round-nearest-even
  return (unsigned short)(u >> 16);
}
static __device__ __forceinline__ float bfbits2f(unsigned int b) {
  return __uint_as_float(b << 16);
}

// ---------------- weight preprocessing ----------------
// w1 [3][128][512] f32 -> w1t [3][512][128] bf16 (n-major, k contiguous)
__global__ void k_w1t(const float* __restrict__ w1, unsigned short* __restrict__ w1t) {
  int idx = blockIdx.x * 256 + threadIdx.x;
  if (idx >= 3 * 512 * 128) return;
  int p = idx >> 16;
  int rem = idx & 65535;
  int n = rem >> 7, k = rem & 127;
  w1t[idx] = f2bf(w1[p * 65536 + k * 512 + n]);
}

// w2 [2][1536][40] f32 -> w2t [80][1536] bf16; col j<40 from w2[0], j>=40 from w2[1]
__global__ void k_w2t(const float* __restrict__ w2, unsigned short* __restrict__ w2t) {
  int idx = blockIdx.x * 256 + threadIdx.x;
  if (idx >= 80 * 1536) return;
  int j = idx / 1536, k = idx % 1536;
  int g  = (j < 40) ? 0 : 1;
  int jj = (j < 40) ? j : j - 40;
  w2t[idx] = f2bf(w2[g * 61440 + k * 40 + jj]);
}

// x f32 -> bf16, float4 granularity
__global__ void k_cvt(const float* __restrict__ src, unsigned short* __restrict__ dst, int n4) {
  int i = blockIdx.x * 256 + threadIdx.x;
  if (i >= n4) return;
  float4 v = ((const float4*)src)[i];
  ushort4 o;
  o.x = f2bf(v.x); o.y = f2bf(v.y); o.z = f2bf(v.z); o.w = f2bf(v.w);
  ((ushort4*)dst)[i] = o;
}

// ---------------- CSR build ----------------
__global__ void k_zero(int* __restrict__ a, int n) {
  int i = blockIdx.x * 256 + threadIdx.x;
  if (i < n) a[i] = 0;
}
__global__ void k_cnt(const int* __restrict__ col, int* __restrict__ cnt, int E) {
  int i = blockIdx.x * 256 + threadIdx.x;
  if (i < E) atomicAdd(&cnt[col[i]], 1);
}
__global__ void k_dinv(const int* __restrict__ cnt, float* __restrict__ dinv, int n) {
  int i = blockIdx.x * 256 + threadIdx.x;
  if (i < n) dinv[i] = rsqrtf((float)(cnt[i] + 1));   // +1 self loop
}

// exclusive scan of cnt[N] -> off[N] (partial within 256-block) + blockSum
__global__ void k_scan1(const int* __restrict__ cnt, int* __restrict__ off,
                        int* __restrict__ blockSum, int N) {
  __shared__ int s[256];
  int t = threadIdx.x, idx = blockIdx.x * 256 + t;
  int val = (idx < N) ? cnt[idx] : 0;
  s[t] = val;
  __syncthreads();
  for (int d = 1; d < 256; d <<= 1) {
    int add = (t >= d) ? s[t - d] : 0;
    __syncthreads();
    s[t] += add;
    __syncthreads();
  }
  if (idx < N) off[idx] = s[t] - val;
  if (t == 255) blockSum[blockIdx.x] = s[255];
}
// single-block scan of blockSum[NB] -> blockOff; writes off[N]=total
__global__ void k_scan2(const int* __restrict__ blockSum, int* __restrict__ blockOff,
                        int* __restrict__ off, int NB, int N) {
  __shared__ int s[1024];
  int t = threadIdx.x;
  int val = (t < NB) ? blockSum[t] : 0;
  s[t] = val;
  __syncthreads();
  for (int d = 1; d < 1024; d <<= 1) {
    int add = (t >= d) ? s[t - d] : 0;
    __syncthreads();
    s[t] += add;
    __syncthreads();
  }
  blockOff[t] = s[t] - val;
  if (t == 1023) off[N] = s[1023];
}
__global__ void k_scan3(int* __restrict__ off, const int* __restrict__ blockOff,
                        int* __restrict__ cursor, int N) {
  int i = blockIdx.x * 256 + threadIdx.x;
  if (i >= N) return;
  int o = off[i] + blockOff[i >> 8];
  off[i] = o;
  cursor[i] = o;
}
// scatter edges into buckets sorted by destination col
__global__ void k_scatter(const int* __restrict__ row, const int* __restrict__ col,
                          const float* __restrict__ dinv, int* __restrict__ cursor,
                          int* __restrict__ rows, float* __restrict__ wts, int E) {
  int e = blockIdx.x * 256 + threadIdx.x;
  if (e >= E) return;
  int r = row[e], c = col[e];
  int pos = atomicAdd(&cursor[c], 1);
  rows[pos] = r;
  wts[pos] = dinv[r] * dinv[c];
}

// ---------------- SpMM gather: dst[c,:] = dinv[c]^2 src[c,:] + sum_e w_e src[r_e,:] ----------------
// width 128 bf16: one wave per node, 2 cols/lane (uint = 2 bf16)
__global__ __launch_bounds__(256) void k_gather128(
    const unsigned short* __restrict__ src, const int* __restrict__ off,
    const int* __restrict__ rows, const float* __restrict__ wts,
    const float* __restrict__ dinv, unsigned short* __restrict__ dst, int N) {
  int c = blockIdx.x * 4 + (threadIdx.x >> 6);
  if (c >= N) return;
  int lane = threadIdx.x & 63;
  const int b = off[c], e = off[c + 1];
  float d = dinv[c];
  unsigned int sv = *(const unsigned int*)(src + (size_t)c * 128 + lane * 2);
  float a0 = d * d * bfbits2f(sv & 0xffffu);
  float a1 = d * d * bfbits2f(sv >> 16);
  int k = b;
  for (; k + 2 <= e; k += 2) {
    int r0 = rows[k], r1 = rows[k + 1];
    float w0 = wts[k], w1 = wts[k + 1];
    unsigned int v0 = *(const unsigned int*)(src + (size_t)r0 * 128 + lane * 2);
    unsigned int v1 = *(const unsigned int*)(src + (size_t)r1 * 128 + lane * 2);
    a0 += w0 * bfbits2f(v0 & 0xffffu) + w1 * bfbits2f(v1 & 0xffffu);
    a1 += w0 * bfbits2f(v0 >> 16)     + w1 * bfbits2f(v1 >> 16);
  }
  if (k < e) {
    int r0 = rows[k];
    float w0 = wts[k];
    unsigned int v0 = *(const unsigned int*)(src + (size_t)r0 * 128 + lane * 2);
    a0 += w0 * bfbits2f(v0 & 0xffffu);
    a1 += w0 * bfbits2f(v0 >> 16);
  }
  unsigned int o = (unsigned int)f2bf(a0) | ((unsigned int)f2bf(a1) << 16);
  *(unsigned int*)(dst + (size_t)c * 128 + lane * 2) = o;
}

// width 40 f32: one wave per node, lanes 0..39
__global__ __launch_bounds__(256) void k_gather40(
    const float* __restrict__ src, const int* __restrict__ off,
    const int* __restrict__ rows, const float* __restrict__ wts,
    const float* __restrict__ dinv, float* __restrict__ dst, int N) {
  int c = blockIdx.x * 4 + (threadIdx.x >> 6);
  if (c >= N) return;
  int lane = threadIdx.x & 63;
  if (lane >= 40) return;
  const int b = off[c], e = off[c + 1];
  float d = dinv[c];
  float acc = d * d * src[(size_t)c * 40 + lane];
  int k = b;
  for (; k + 2 <= e; k += 2) {
    int r0 = rows[k], r1 = rows[k + 1];
    float w0 = wts[k], w1 = wts[k + 1];
    acc += w0 * src[(size_t)r0 * 40 + lane] + w1 * src[(size_t)r1 * 40 + lane];
  }
  if (k < e) acc += wts[k] * src[(size_t)rows[k] * 40 + lane];
  dst[(size_t)c * 40 + lane] = acc;
}

// ---------------- GEMM 1: H[:,col0:col0+512] = relu(A[M,128]bf16 @ B + b1), bf16 out ----------------
// block: 256 thr (4 waves), 64 rows; wave w owns cols [w*128, +128)
__global__ __launch_bounds__(256) void k_gemm1(
    const unsigned short* __restrict__ A, const unsigned short* __restrict__ Bt,
    const float* __restrict__ bias, unsigned short* __restrict__ H,
    int M, int col0) {
  const int tid = threadIdx.x, wave = tid >> 6, lane = tid & 63;
  const int lhi = lane >> 4, llo = lane & 15;
  const int row0 = blockIdx.x * 64;
  f4v acc[4][8];
#pragma unroll
  for (int i = 0; i < 4; ++i)
#pragma unroll
    for (int j = 0; j < 8; ++j) acc[i][j] = (f4v){0.f, 0.f, 0.f, 0.f};
  size_t arow[4];
#pragma unroll
  for (int i = 0; i < 4; ++i) {
    int r = row0 + i * 16 + llo; if (r > M - 1) r = M - 1;
    arow[i] = (size_t)r * 128 + lhi * 8;
  }
  const unsigned short* Bw = Bt + (size_t)(wave * 128 + llo) * 128 + lhi * 8;
#pragma unroll
  for (int kk = 0; kk < 128; kk += 32) {
    s8v a[4], b[8];
#pragma unroll
    for (int i = 0; i < 4; ++i) a[i] = *(const s8v*)(A + arow[i] + kk);
#pragma unroll
    for (int j = 0; j < 8; ++j) b[j] = *(const s8v*)(Bw + (size_t)j * 16 * 128 + kk);
#pragma unroll
    for (int i = 0; i < 4; ++i)
#pragma unroll
      for (int j = 0; j < 8; ++j)
        acc[i][j] = __builtin_amdgcn_mfma_f32_16x16x32_bf16(a[i], b[j], acc[i][j], 0, 0, 0);
  }
#pragma unroll
  for (int i = 0; i < 4; ++i) {
#pragma unroll
    for (int j = 0; j < 8; ++j) {
      int colg = col0 + wave * 128 + j * 16 + llo;
      float bv = bias[colg];
#pragma unroll
      for (int r = 0; r < 4; ++r) {
        int rowg = row0 + i * 16 + lhi * 4 + r;
        if (rowg < M) {
          float v = acc[i][j][r] + bv;
          H[(size_t)rowg * 1536 + colg] = f2bf(v > 0.f ? v : 0.f);
        }
      }
    }
  }
}

// ---------------- GEMM 2: [M,1536]bf16 @ [1536,80] -> t0(+b2) into out[:,0:40], t1 f32 ----------------
__global__ __launch_bounds__(256) void k_gemm2(
    const unsigned short* __restrict__ Hm, const unsigned short* __restrict__ Bt,
    const float* __restrict__ b2, float* __restrict__ out, float* __restrict__ t1, int M) {
  const int tid = threadIdx.x, wave = tid >> 6, lane = tid & 63;
  const int lhi = lane >> 4, llo = lane & 15;
  const int row0 = blockIdx.x * 256 + wave * 64;
  f4v acc[4][5];
#pragma unroll
  for (int i = 0; i < 4; ++i)
#pragma unroll
    for (int j = 0; j < 5; ++j) acc[i][j] = (f4v){0.f, 0.f, 0.f, 0.f};
  size_t arow[4];
#pragma unroll
  for (int i = 0; i < 4; ++i) {
    int r = row0 + i * 16 + llo; if (r > M - 1) r = M - 1;
    arow[i] = (size_t)r * 1536 + lhi * 8;
  }
  const unsigned short* Bw = Bt + (size_t)llo * 1536 + lhi * 8;
  for (int kk = 0; kk < 1536; kk += 32) {
    s8v a[4], b[5];
#pragma unroll
    for (int i = 0; i < 4; ++i) a[i] = *(const s8v*)(Hm + arow[i] + kk);
#pragma unroll
    for (int j = 0; j < 5; ++j) b[j] = *(const s8v*)(Bw + (size_t)j * 16 * 1536 + kk);
#pragma unroll
    for (int i = 0; i < 4; ++i)
#pragma unroll
      for (int j = 0; j < 5; ++j)
        acc[i][j] = __builtin_amdgcn_mfma_f32_16x16x32_bf16(a[i], b[j], acc[i][j], 0, 0, 0);
  }
#pragma unroll
  for (int i = 0; i < 4; ++i)
#pragma unroll
    for (int j = 0; j < 5; ++j) {
      int col = j * 16 + llo;
#pragma unroll
      for (int r = 0; r < 4; ++r) {
        int rowg = row0 + i * 16 + lhi * 4 + r;
        if (rowg < M) {
          float v = acc[i][j][r];
          if (col < 40) out[(size_t)rowg * 80 + col] = v + b2[col];
          else          t1[(size_t)rowg * 40 + col - 40] = v;
        }
      }
    }
}

// ---------------- log_softmax over 80 cols; one wave per row ----------------
__global__ void k_logsm(float* __restrict__ out, const float* __restrict__ u1,
                        const float* __restrict__ b2, int N) {
  int n = blockIdx.x * 4 + (threadIdx.x >> 6);
  if (n >= N) return;
  int lane = threadIdx.x & 63;
  float v0, v1;
  if (lane < 40) v0 = out[(size_t)n * 80 + lane];
  else           v0 = u1[(size_t)n * 40 + lane - 40] + b2[lane];
  v1 = (lane < 16) ? (u1[(size_t)n * 40 + 24 + lane] + b2[64 + lane]) : -INFINITY;
  float m = fmaxf(v0, v1);
#pragma unroll
  for (int s = 32; s > 0; s >>= 1) m = fmaxf(m, __shfl_xor(m, s));
  float s = __expf(v0 - m) + ((lane < 16) ? __expf(v1 - m) : 0.f);
#pragma unroll
  for (int sft = 32; sft > 0; sft >>= 1) s += __shfl_xor(s, sft);
  float L = m + __logf(s);
  out[(size_t)n * 80 + lane] = v0 - L;
  if (lane < 16) out[(size_t)n * 80 + 64 + lane] = v1 - L;
}

// ---------------- launch ----------------
extern "C" void kernel_launch(void* const* d_in, const int* in_sizes, int n_in,
                              void* d_out, int out_size, void* d_ws, size_t ws_size,
                              hipStream_t stream) {
  const float* x  = (const float*)d_in[0];
  const int*   ei = (const int*)d_in[1];
  const float* w1 = (const float*)d_in[2];
  const float* b1 = (const float*)d_in[3];
  const float* w2 = (const float*)d_in[4];
  const float* b2 = (const float*)d_in[5];
  float* out = (float*)d_out;

  const int N = in_sizes[0] / 128;
  const int E = in_sizes[1] / 2;
  const int* erow = ei;
  const int* ecol = ei + E;
  const int NB = CDIV(N, 256);

  // workspace carve (256B aligned); fixed ~180 MB, Hb chunk from remainder
  char* p = (char*)d_ws;
  auto carve = [&](size_t bytes) { void* r = (void*)p; p += (bytes + 255) & ~(size_t)255; return r; };
  int*            cnt  = (int*)carve((size_t)N * 4);
  float*          dinv = (float*)carve((size_t)N * 4);
  int*            off  = (int*)carve((size_t)(N + 1) * 4);
  int*            cur  = (int*)carve((size_t)N * 4);
  int*            bsum = (int*)carve(1024 * 4);
  int*            boff = (int*)carve(1024 * 4);
  int*            rows = (int*)carve((size_t)E * 4);
  float*          wts  = (float*)carve((size_t)E * 4);
  unsigned short* xb   = (unsigned short*)carve((size_t)N * 128 * 2);
  unsigned short* h1b  = (unsigned short*)carve((size_t)N * 128 * 2);
  unsigned short* h2b  = (unsigned short*)carve((size_t)N * 128 * 2);
  float*          t1   = (float*)carve((size_t)N * 40 * 4);
  unsigned short* w1t  = (unsigned short*)carve((size_t)3 * 512 * 128 * 2);
  unsigned short* w2t  = (unsigned short*)carve((size_t)80 * 1536 * 2);
  float*          u1   = (float*)h2b;   // h2b dead after chunk loop

  size_t usedB = (size_t)(p - (char*)d_ws);
  size_t remB  = (ws_size > usedB + (1u << 20)) ? (ws_size - usedB - (1u << 20)) : 0;
  long long cap = (long long)(remB / (1536 * 2));
  int Cmax = (cap >= (long long)N) ? N : (int)cap;
  Cmax &= ~63;
  if (Cmax < 64) Cmax = 64;
  unsigned short* Hb = (unsigned short*)carve((size_t)Cmax * 1536 * 2);

  // weights + x -> bf16
  k_w1t<<<CDIV(3 * 512 * 128, 256), 256, 0, stream>>>(w1, w1t);
  k_w2t<<<CDIV(80 * 1536, 256), 256, 0, stream>>>(w2, w2t);
  k_cvt<<<CDIV(N * 32, 256), 256, 0, stream>>>(x, xb, N * 32);

  // CSR build (sorted by destination col) + dinv
  k_zero<<<CDIV(N, 256), 256, 0, stream>>>(cnt, N);
  k_cnt<<<CDIV(E, 256), 256, 0, stream>>>(ecol, cnt, E);
  k_dinv<<<CDIV(N, 256), 256, 0, stream>>>(cnt, dinv, N);
  k_scan1<<<NB, 256, 0, stream>>>(cnt, off, bsum, N);
  k_scan2<<<1, 1024, 0, stream>>>(bsum, boff, off, NB, N);
  k_scan3<<<CDIV(N, 256), 256, 0, stream>>>(off, boff, cur, N);
  k_scatter<<<CDIV(E, 256), 256, 0, stream>>>(erow, ecol, dinv, cur, rows, wts, E);

  // h1 = A_hat x ; h2 = A_hat h1   (bf16 gather, width 128)
  k_gather128<<<CDIV(N, 4), 256, 0, stream>>>(xb,  off, rows, wts, dinv, h1b, N);
  k_gather128<<<CDIV(N, 4), 256, 0, stream>>>(h1b, off, rows, wts, dinv, h2b, N);

  // chunked: H = relu(concat(xW0,h1W1,h2W2)+b1); t0 -> out[:,0:40]+b2; t1 = H @ w2[1]
  for (int r0 = 0; r0 < N; r0 += Cmax) {
    int Mc = (N - r0 < Cmax) ? (N - r0) : Cmax;
    int g1 = CDIV(Mc, 64);
    k_gemm1<<<g1, 256, 0, stream>>>(xb  + (size_t)r0 * 128, w1t,          b1, Hb, Mc, 0);
    k_gemm1<<<g1, 256, 0, stream>>>(h1b + (size_t)r0 * 128, w1t +  65536, b1, Hb, Mc, 512);
    k_gemm1<<<g1, 256, 0, stream>>>(h2b + (size_t)r0 * 128, w1t + 131072, b1, Hb, Mc, 1024);
    k_gemm2<<<CDIV(Mc, 256), 256, 0, stream>>>(Hb, w2t, b2,
                                               out + (size_t)r0 * 80,
                                               t1  + (size_t)r0 * 40, Mc);
  }

  // u1 = A_hat t1  (f32 gather, width 40); u1 aliases h2b (dead now)
  k_gather40<<<CDIV(N, 4), 256, 0, stream>>>(t1, off, rows, wts, dinv, u1, N);

  // out = log_softmax([t0+b2[0:40], u1+b2[40:80]])
  k_logsm<<<CDIV(N, 4), 256, 0, stream>>>(out, u1, b2, N);
}